// Round 3
// baseline (750.049 us; speedup 1.0000x reference)
//
#include <hip/hip_runtime.h>

typedef __attribute__((ext_vector_type(8))) short short8;
typedef __attribute__((ext_vector_type(4))) float floatx4;

__device__ __forceinline__ float bf2f(short u) {
  unsigned int i = ((unsigned int)(unsigned short)u) << 16;
  return __builtin_bit_cast(float, i);
}
__device__ __forceinline__ short f2bf(float f) {
  unsigned int x = __builtin_bit_cast(unsigned int, f);
  x += 0x7fffu + ((x >> 16) & 1u);
  return (short)(x >> 16);
}

// Batch processed in chunks of BC=256 rows to keep workspace small.
#define BC 256

// ---- gather: x[B,6400,2] f32 -> hA[64][BC][224] bf16 (K padded 200->224) -----
__global__ __launch_bounds__(256) void gather_x(const float* __restrict__ x,
                                                short* __restrict__ hA, int bOffset) {
  int tid = blockIdx.x * 256 + threadIdx.x;
  const int total = 64 * BC * 224;
  if (tid >= total) return;
  int kp = tid % 224;
  int rem = tid / 224;
  int b_loc = rem & (BC - 1);
  int j1 = rem / BC;
  short v = 0;
  if (kp < 200) {
    int c = kp & 1;
    int w = kp >> 1;
    int wx = w / 10;
    int wy = w - wx * 10;
    int bx = j1 >> 3, by = j1 & 7;
    v = f2bf(x[(size_t)(bOffset + b_loc) * 12800 +
               ((size_t)(bx * 800 + wx * 80 + by * 10 + wy)) * 2 + c]);
  }
  hA[tid] = v;
}

// ---- k1[64][200][1024] f32 -> k1t[64][1024][224] bf16 (B^T, zero-padded) -----
__global__ __launch_bounds__(256) void transpose_k1(const float* __restrict__ k1,
                                                    short* __restrict__ k1t) {
  int g = blockIdx.x * 256 + threadIdx.x;  // [0, 65536) over (j1, n)
  int n = g & 1023;
  int j1 = g >> 10;
  int k0base = blockIdx.y * 32;
  const float* src = k1 + (size_t)j1 * (200 * 1024) + n;
  short* dst = k1t + (size_t)g * 224;
  for (int k0 = k0base; k0 < k0base + 32; k0 += 8) {
    short8 v;
#pragma unroll
    for (int i = 0; i < 8; ++i) {
      int k = k0 + i;
      v[i] = (k < 200) ? f2bf(src[k * 1024]) : (short)0;
    }
    *(short8*)&dst[k0] = v;
  }
}

// ---- k3[64][1024][200] f32 -> k3t[64][256][1024] bf16 (B^T, N padded) --------
__global__ __launch_bounds__(256) void transpose_k3(const float* __restrict__ k3,
                                                    short* __restrict__ k3t) {
  int g = blockIdx.x * 256 + threadIdx.x;  // [0, 16384) over (j3, n)
  int n = g & 255;
  int j3 = g >> 8;
  int kbase = blockIdx.y * 128;
  const float* src = k3 + (size_t)j3 * (1024 * 200) + n;
  short* dst = k3t + (size_t)g * 1024;
  bool valid = (n < 200);
  for (int k0 = kbase; k0 < kbase + 128; k0 += 8) {
    short8 v;
#pragma unroll
    for (int i = 0; i < 8; ++i)
      v[i] = valid ? f2bf(src[(k0 + i) * 200]) : (short)0;
    *(short8*)&dst[k0] = v;
  }
}

// ---- stage 1: per j1, C[BC,1024] = A[BC,224] @ Bt[1024,224]^T + b1 -----------
__global__ __launch_bounds__(256) void gemm_stage1(const short* __restrict__ hA,
                                                   const short* __restrict__ k1t,
                                                   const float* __restrict__ b1,
                                                   short* __restrict__ h1) {
  const int j1 = blockIdx.z;
  const int mBase = blockIdx.y * 64;
  const int nBase = blockIdx.x * 64;
  __shared__ short As[64][40];
  __shared__ short Bs[64][40];
  const int tid = threadIdx.x;
  const int wave = tid >> 6;
  const int lane = tid & 63;
  const int quad = lane >> 4;
  const int l16 = lane & 15;
  const int row = tid >> 2;
  const int kofs = (tid & 3) * 8;
  const short* Aj = hA + (size_t)j1 * BC * 224;
  const short* Bj = k1t + (size_t)j1 * 1024 * 224;
  floatx4 acc[4] = {};

  for (int kk = 0; kk < 224; kk += 32) {
    *(short8*)&As[row][kofs] = *(const short8*)&Aj[(mBase + row) * 224 + kk + kofs];
    *(short8*)&Bs[row][kofs] = *(const short8*)&Bj[(nBase + row) * 224 + kk + kofs];
    __syncthreads();
    short8 af = *(const short8*)&As[wave * 16 + l16][quad * 8];
#pragma unroll
    for (int nt = 0; nt < 4; ++nt) {
      short8 bf = *(const short8*)&Bs[nt * 16 + l16][quad * 8];
      acc[nt] = __builtin_amdgcn_mfma_f32_16x16x32_bf16(af, bf, acc[nt], 0, 0, 0);
    }
    __syncthreads();
  }
#pragma unroll
  for (int nt = 0; nt < 4; ++nt) {
    int n = nBase + nt * 16 + l16;
    float bias = b1[j1 * 1024 + n];
#pragma unroll
    for (int r = 0; r < 4; ++r) {
      int m = mBase + wave * 16 + quad * 4 + r;
      h1[((size_t)j1 * BC + m) * 1024 + n] = f2bf(acc[nt][r] + bias);
    }
  }
}

// ---- stage 2: permute + tiny GEMMs, h1[64][BC][1024] -> h2p[64][BC][1024] ----
__global__ __launch_bounds__(256) void stage2(const short* __restrict__ h1,
                                              const float* __restrict__ k2,
                                              const float* __restrict__ b2,
                                              short* __restrict__ h2p) {
  const int j1 = blockIdx.x;
  const int bBase = blockIdx.y * 8;
  __shared__ short in_s[8][1024];    // 16,384 B
  __shared__ short w_s[256 * 66];    // 33,792 B  [within=k*16+r2][blk=r*4+b2hi]
  __shared__ float bias_s[16 * 64];  //  4,096 B  [r2][blk]   (total 54,272 B)
  const int tid = threadIdx.x;
#pragma unroll
  for (int ii = 0; ii < 4; ++ii) {
    int flat = (ii * 256 + tid) * 8;  // 8*1024 elements
    int b_loc = flat >> 10;
    int k = flat & 1023;
    *(short8*)&in_s[b_loc][k] =
        *(const short8*)&h1[((size_t)j1 * BC + bBase + b_loc) * 1024 + k];
  }
#pragma unroll
  for (int ii = 0; ii < 16; ++ii) {
    int flat = (ii * 256 + tid) * 4;  // 64*256 weight f32 elements
    int blk = flat >> 8;
    int within = flat & 255;
    int r = blk >> 2, b2hi = blk & 3;
    int j2 = r * 256 + j1 * 4 + b2hi;
    floatx4 v = *(const floatx4*)&k2[(size_t)j2 * 256 + within];
#pragma unroll
    for (int i = 0; i < 4; ++i) w_s[(within + i) * 66 + blk] = f2bf(v[i]);
  }
  {
    int blk = tid >> 2;
    int r2o = (tid & 3) * 4;
    int r = blk >> 2, b2hi = blk & 3;
    int j2 = r * 256 + j1 * 4 + b2hi;
#pragma unroll
    for (int i = 0; i < 4; ++i) bias_s[(r2o + i) * 64 + blk] = b2[j2 * 16 + r2o + i];
  }
  __syncthreads();
#pragma unroll
  for (int i4 = 0; i4 < 2; ++i4) {
    int idx = i4 * 256 + tid;  // 8 b_loc x 64 (r,b2hi)
    int b_loc = idx >> 6;
    int rem = idx & 63;
    int r = rem >> 2;
    int b2hi = rem & 3;
    float acc[16];
#pragma unroll
    for (int r2 = 0; r2 < 16; ++r2) acc[r2] = bias_s[r2 * 64 + rem];
#pragma unroll
    for (int k = 0; k < 16; ++k) {
      float iv = bf2f(in_s[b_loc][(b2hi * 16 + k) * 16 + r]);
#pragma unroll
      for (int r2 = 0; r2 < 16; ++r2)
        acc[r2] += iv * bf2f(w_s[(k * 16 + r2) * 66 + rem]);
    }
    int j3 = r * 4 + (j1 >> 4);
    int k3o = (j1 & 15) * 64 + b2hi * 16;
    short8 o0, o1;
#pragma unroll
    for (int t = 0; t < 8; ++t) {
      o0[t] = f2bf(acc[t]);
      o1[t] = f2bf(acc[8 + t]);
    }
    short* dst = h2p + ((size_t)j3 * BC + bBase + b_loc) * 1024 + k3o;
    *(short8*)&dst[0] = o0;
    *(short8*)&dst[8] = o1;
  }
}

// ---- stage 3: per j3, [BC,1024] @ k3t^T (+b3 f32), scatter to out f32 --------
__global__ __launch_bounds__(256) void gemm_stage3(const short* __restrict__ h2p,
                                                   const short* __restrict__ k3t,
                                                   const float* __restrict__ b3,
                                                   float* __restrict__ out, int bOffset) {
  const int j3 = blockIdx.z;
  const int mBase = blockIdx.y * 64;
  const int nBase = blockIdx.x * 64;
  __shared__ short As[64][40];
  __shared__ short Bs[64][40];
  const int tid = threadIdx.x;
  const int wave = tid >> 6;
  const int lane = tid & 63;
  const int quad = lane >> 4;
  const int l16 = lane & 15;
  const int row = tid >> 2;
  const int kofs = (tid & 3) * 8;
  const short* Aj = h2p + (size_t)j3 * BC * 1024;
  const short* Bj = k3t + (size_t)j3 * 256 * 1024;
  floatx4 acc[4] = {};

  for (int kk = 0; kk < 1024; kk += 32) {
    *(short8*)&As[row][kofs] = *(const short8*)&Aj[(mBase + row) * 1024 + kk + kofs];
    *(short8*)&Bs[row][kofs] = *(const short8*)&Bj[(nBase + row) * 1024 + kk + kofs];
    __syncthreads();
    short8 af = *(const short8*)&As[wave * 16 + l16][quad * 8];
#pragma unroll
    for (int nt = 0; nt < 4; ++nt) {
      short8 bf = *(const short8*)&Bs[nt * 16 + l16][quad * 8];
      acc[nt] = __builtin_amdgcn_mfma_f32_16x16x32_bf16(af, bf, acc[nt], 0, 0, 0);
    }
    __syncthreads();
  }
  const int B2x = j3 >> 3, B2y = j3 & 7;
#pragma unroll
  for (int nt = 0; nt < 4; ++nt) {
    int n = nBase + nt * 16 + l16;
    if (n < 200) {
      float bias = b3[j3 * 200 + n];
      int c = n & 1;
      int t = n >> 1;
      int w2x = t / 10, w2y = t - w2x * 10;
      int orow = B2x * 10 + w2x, ocol = B2y * 10 + w2y;
#pragma unroll
      for (int r = 0; r < 4; ++r) {
        int m = bOffset + mBase + wave * 16 + quad * 4 + r;
        out[(((size_t)m * 80 + orow) * 80 + ocol) * 2 + c] = acc[nt][r] + bias;
      }
    }
  }
}

extern "C" void kernel_launch(void* const* d_in, const int* in_sizes, int n_in,
                              void* d_out, int out_size, void* d_ws, size_t ws_size,
                              hipStream_t stream) {
  const float* x = (const float*)d_in[0];
  const float* k1 = (const float*)d_in[1];
  const float* b1 = (const float*)d_in[2];
  const float* k2 = (const float*)d_in[3];
  const float* b2 = (const float*)d_in[4];
  const float* k3 = (const float*)d_in[5];
  const float* b3 = (const float*)d_in[6];
  float* out = (float*)d_out;
  char* ws = (char*)d_ws;

  // Workspace layout (137,363,456 bytes total), all bf16:
  short* k1t = (short*)(ws);                 // 64*1024*224*2 = 29,360,128
  short* k3t = (short*)(ws + 29360128);      // 64*256*1024*2 = 33,554,432
  short* hA = (short*)(ws + 62914560);       // 64*BC*224*2   =  7,340,032
  short* h1c = (short*)(ws + 70254592);      // 64*BC*1024*2  = 33,554,432
  short* h2pc = (short*)(ws + 103809024);    // 64*BC*1024*2  = 33,554,432

  transpose_k1<<<dim3(256, 7), 256, 0, stream>>>(k1, k1t);
  transpose_k3<<<dim3(64, 8), 256, 0, stream>>>(k3, k3t);
  for (int c = 0; c < 1024 / BC; ++c) {
    int bOffset = c * BC;
    gather_x<<<(64 * BC * 224) / 256, 256, 0, stream>>>(x, hA, bOffset);
    gemm_stage1<<<dim3(16, BC / 64, 64), 256, 0, stream>>>(hA, k1t, b1, h1c);
    stage2<<<dim3(64, BC / 8), 256, 0, stream>>>(h1c, k2, b2, h2pc);
    gemm_stage3<<<dim3(4, BC / 64, 64), 256, 0, stream>>>(h2pc, k3t, b3, out, bOffset);
  }
}

// Round 5
// 660.118 us; speedup vs baseline: 1.1362x; 1.1362x over previous
//
#include <hip/hip_runtime.h>

typedef __attribute__((ext_vector_type(8))) short short8;
typedef __attribute__((ext_vector_type(4))) short bfx4;
typedef __attribute__((ext_vector_type(4))) float floatx4;

__device__ __forceinline__ float bf2f(short u) {
  unsigned int i = ((unsigned int)(unsigned short)u) << 16;
  return __builtin_bit_cast(float, i);
}
__device__ __forceinline__ short f2bf(float f) {
  unsigned int x = __builtin_bit_cast(unsigned int, f);
  x += 0x7fffu + ((x >> 16) & 1u);
  return (short)(x >> 16);
}

// Batch processed in chunks of BC=256 rows to keep workspace small.
#define BC 256

// ---- gather: x[B,6400,2] f32 -> hA[64][BC][224] bf16 (K padded 200->224) -----
__global__ __launch_bounds__(256) void gather_x(const float* __restrict__ x,
                                                short* __restrict__ hA, int bOffset) {
  int tid = blockIdx.x * 256 + threadIdx.x;
  const int total = 64 * BC * 224;
  if (tid >= total) return;
  int kp = tid % 224;
  int rem = tid / 224;
  int b_loc = rem & (BC - 1);
  int j1 = rem / BC;
  short v = 0;
  if (kp < 200) {
    int c = kp & 1;
    int w = kp >> 1;
    int wx = w / 10;
    int wy = w - wx * 10;
    int bx = j1 >> 3, by = j1 & 7;
    v = f2bf(x[(size_t)(bOffset + b_loc) * 12800 +
               ((size_t)(bx * 800 + wx * 80 + by * 10 + wy)) * 2 + c]);
  }
  hA[tid] = v;
}

// ---- k1[64][200][1024] f32 -> k1t[64][1024][224] bf16 (B^T, zero-padded) -----
// LDS-tiled: coalesced reads (n-major) AND coalesced writes (k-contiguous rows).
__global__ __launch_bounds__(256) void transpose_k1(const float* __restrict__ k1,
                                                    short* __restrict__ k1t) {
  const int j1 = blockIdx.x;        // 64
  const int nBase = blockIdx.y * 64;  // 16 tiles over n=1024
  __shared__ short tr[64][228];     // row stride 228 shorts (456 B, 8B-aligned)
  const int t = threadIdx.x;
  const int nl = t & 63;
  const int ksub = t >> 6;
  const float* src = k1 + (size_t)j1 * 204800 + nBase + nl;
#pragma unroll 4
  for (int pass = 0; pass < 56; ++pass) {
    int k = pass * 4 + ksub;
    tr[nl][k] = (k < 200) ? f2bf(src[k * 1024]) : (short)0;
  }
  __syncthreads();
  // 64 rows x 224 k = 3584 bfx4 units; 256 threads -> 14 passes
  short* dstbase = k1t + ((size_t)j1 * 1024 + nBase) * 224;
#pragma unroll
  for (int pass = 0; pass < 14; ++pass) {
    int idx = (pass * 256 + t) * 4;
    int row = idx / 224;
    int koff = idx - row * 224;
    bfx4 v = *(const bfx4*)&tr[row][koff];
    *(bfx4*)&dstbase[row * 224 + koff] = v;
  }
}

// ---- k3[64][1024][200] f32 -> k3t[64][256][1024] bf16 (B^T, N padded) --------
// LDS-tiled 128k x 64n.
__global__ __launch_bounds__(256) void transpose_k3(const float* __restrict__ k3,
                                                    short* __restrict__ k3t) {
  const int j3 = blockIdx.x;           // 64
  const int kBase = blockIdx.y * 128;  // 8 tiles over k=1024
  const int nBase = blockIdx.z * 64;   // 4 tiles over n=256 (200 valid)
  __shared__ short tr[64][132];        // row stride 132 shorts (264 B, 8B-aligned)
  const int t = threadIdx.x;
  const int nl = t & 63;
  const int ksub = t >> 6;
  const int nGlob = nBase + nl;
  const bool valid = (nGlob < 200);
  const float* src = k3 + (size_t)j3 * 204800 + (size_t)kBase * 200 + nGlob;
#pragma unroll 4
  for (int pass = 0; pass < 32; ++pass) {
    int k = pass * 4 + ksub;
    tr[nl][k] = valid ? f2bf(src[k * 200]) : (short)0;
  }
  __syncthreads();
  // 64 rows x 128 k = 2048 bfx4 units; 256 threads -> 8 passes
  short* dstbase = k3t + ((size_t)j3 * 256 + nBase) * 1024 + kBase;
#pragma unroll
  for (int pass = 0; pass < 8; ++pass) {
    int idx = (pass * 256 + t) * 4;
    int row = idx >> 7;
    int koff = idx & 127;
    bfx4 v = *(const bfx4*)&tr[row][koff];
    *(bfx4*)&dstbase[row * 1024 + koff] = v;
  }
}

// ---- stage 1: per j1, C[BC,1024] = A[BC,224] @ Bt[1024,224]^T + b1 -----------
__global__ __launch_bounds__(256) void gemm_stage1(const short* __restrict__ hA,
                                                   const short* __restrict__ k1t,
                                                   const float* __restrict__ b1,
                                                   short* __restrict__ h1) {
  const int j1 = blockIdx.z;
  const int mBase = blockIdx.y * 64;
  const int nBase = blockIdx.x * 64;
  __shared__ short As[64][40];
  __shared__ short Bs[64][40];
  const int tid = threadIdx.x;
  const int wave = tid >> 6;
  const int lane = tid & 63;
  const int quad = lane >> 4;
  const int l16 = lane & 15;
  const int row = tid >> 2;
  const int kofs = (tid & 3) * 8;
  const short* Aj = hA + (size_t)j1 * BC * 224;
  const short* Bj = k1t + (size_t)j1 * 1024 * 224;
  floatx4 acc[4] = {};

  for (int kk = 0; kk < 224; kk += 32) {
    *(short8*)&As[row][kofs] = *(const short8*)&Aj[(mBase + row) * 224 + kk + kofs];
    *(short8*)&Bs[row][kofs] = *(const short8*)&Bj[(nBase + row) * 224 + kk + kofs];
    __syncthreads();
    short8 af = *(const short8*)&As[wave * 16 + l16][quad * 8];
#pragma unroll
    for (int nt = 0; nt < 4; ++nt) {
      short8 bf = *(const short8*)&Bs[nt * 16 + l16][quad * 8];
      acc[nt] = __builtin_amdgcn_mfma_f32_16x16x32_bf16(af, bf, acc[nt], 0, 0, 0);
    }
    __syncthreads();
  }
#pragma unroll
  for (int nt = 0; nt < 4; ++nt) {
    int n = nBase + nt * 16 + l16;
    float bias = b1[j1 * 1024 + n];
#pragma unroll
    for (int r = 0; r < 4; ++r) {
      int m = mBase + wave * 16 + quad * 4 + r;
      h1[((size_t)j1 * BC + m) * 1024 + n] = f2bf(acc[nt][r] + bias);
    }
  }
}

// ---- stage 2: permute + tiny GEMMs, h1[64][BC][1024] -> h2p[64][BC][1024] ----
__global__ __launch_bounds__(256) void stage2(const short* __restrict__ h1,
                                              const float* __restrict__ k2,
                                              const float* __restrict__ b2,
                                              short* __restrict__ h2p) {
  const int j1 = blockIdx.x;
  const int bBase = blockIdx.y * 8;
  __shared__ short in_s[8][1024];    // 16,384 B
  __shared__ short w_s[256 * 66];    // 33,792 B  [within=k*16+r2][blk=r*4+b2hi]
  __shared__ float bias_s[16 * 64];  //  4,096 B  [r2][blk]   (total 54,272 B)
  const int tid = threadIdx.x;
#pragma unroll
  for (int ii = 0; ii < 4; ++ii) {
    int flat = (ii * 256 + tid) * 8;  // 8*1024 elements
    int b_loc = flat >> 10;
    int k = flat & 1023;
    *(short8*)&in_s[b_loc][k] =
        *(const short8*)&h1[((size_t)j1 * BC + bBase + b_loc) * 1024 + k];
  }
#pragma unroll
  for (int ii = 0; ii < 16; ++ii) {
    int flat = (ii * 256 + tid) * 4;  // 64*256 weight f32 elements
    int blk = flat >> 8;
    int within = flat & 255;
    int r = blk >> 2, b2hi = blk & 3;
    int j2 = r * 256 + j1 * 4 + b2hi;
    floatx4 v = *(const floatx4*)&k2[(size_t)j2 * 256 + within];
#pragma unroll
    for (int i = 0; i < 4; ++i) w_s[(within + i) * 66 + blk] = f2bf(v[i]);
  }
  {
    int blk = tid >> 2;
    int r2o = (tid & 3) * 4;
    int r = blk >> 2, b2hi = blk & 3;
    int j2 = r * 256 + j1 * 4 + b2hi;
#pragma unroll
    for (int i = 0; i < 4; ++i) bias_s[(r2o + i) * 64 + blk] = b2[j2 * 16 + r2o + i];
  }
  __syncthreads();
#pragma unroll
  for (int i4 = 0; i4 < 2; ++i4) {
    int idx = i4 * 256 + tid;  // 8 b_loc x 64 (r,b2hi)
    int b_loc = idx >> 6;
    int rem = idx & 63;
    int r = rem >> 2;
    int b2hi = rem & 3;
    float acc[16];
#pragma unroll
    for (int r2 = 0; r2 < 16; ++r2) acc[r2] = bias_s[r2 * 64 + rem];
#pragma unroll
    for (int k = 0; k < 16; ++k) {
      float iv = bf2f(in_s[b_loc][(b2hi * 16 + k) * 16 + r]);
#pragma unroll
      for (int r2 = 0; r2 < 16; ++r2)
        acc[r2] += iv * bf2f(w_s[(k * 16 + r2) * 66 + rem]);
    }
    int j3 = r * 4 + (j1 >> 4);
    int k3o = (j1 & 15) * 64 + b2hi * 16;
    short8 o0, o1;
#pragma unroll
    for (int t = 0; t < 8; ++t) {
      o0[t] = f2bf(acc[t]);
      o1[t] = f2bf(acc[8 + t]);
    }
    short* dst = h2p + ((size_t)j3 * BC + bBase + b_loc) * 1024 + k3o;
    *(short8*)&dst[0] = o0;
    *(short8*)&dst[8] = o1;
  }
}

// ---- stage 3: per j3, [BC,1024] @ k3t^T (+b3 f32), scatter to out f32 --------
__global__ __launch_bounds__(256) void gemm_stage3(const short* __restrict__ h2p,
                                                   const short* __restrict__ k3t,
                                                   const float* __restrict__ b3,
                                                   float* __restrict__ out, int bOffset) {
  const int j3 = blockIdx.z;
  const int mBase = blockIdx.y * 64;
  const int nBase = blockIdx.x * 64;
  __shared__ short As[64][40];
  __shared__ short Bs[64][40];
  const int tid = threadIdx.x;
  const int wave = tid >> 6;
  const int lane = tid & 63;
  const int quad = lane >> 4;
  const int l16 = lane & 15;
  const int row = tid >> 2;
  const int kofs = (tid & 3) * 8;
  const short* Aj = h2p + (size_t)j3 * BC * 1024;
  const short* Bj = k3t + (size_t)j3 * 256 * 1024;
  floatx4 acc[4] = {};

  for (int kk = 0; kk < 1024; kk += 32) {
    *(short8*)&As[row][kofs] = *(const short8*)&Aj[(mBase + row) * 1024 + kk + kofs];
    *(short8*)&Bs[row][kofs] = *(const short8*)&Bj[(nBase + row) * 1024 + kk + kofs];
    __syncthreads();
    short8 af = *(const short8*)&As[wave * 16 + l16][quad * 8];
#pragma unroll
    for (int nt = 0; nt < 4; ++nt) {
      short8 bf = *(const short8*)&Bs[nt * 16 + l16][quad * 8];
      acc[nt] = __builtin_amdgcn_mfma_f32_16x16x32_bf16(af, bf, acc[nt], 0, 0, 0);
    }
    __syncthreads();
  }
  const int B2x = j3 >> 3, B2y = j3 & 7;
#pragma unroll
  for (int nt = 0; nt < 4; ++nt) {
    int n = nBase + nt * 16 + l16;
    if (n < 200) {
      float bias = b3[j3 * 200 + n];
      int c = n & 1;
      int t = n >> 1;
      int w2x = t / 10, w2y = t - w2x * 10;
      int orow = B2x * 10 + w2x, ocol = B2y * 10 + w2y;
#pragma unroll
      for (int r = 0; r < 4; ++r) {
        int m = bOffset + mBase + wave * 16 + quad * 4 + r;
        out[(((size_t)m * 80 + orow) * 80 + ocol) * 2 + c] = acc[nt][r] + bias;
      }
    }
  }
}

extern "C" void kernel_launch(void* const* d_in, const int* in_sizes, int n_in,
                              void* d_out, int out_size, void* d_ws, size_t ws_size,
                              hipStream_t stream) {
  const float* x = (const float*)d_in[0];
  const float* k1 = (const float*)d_in[1];
  const float* b1 = (const float*)d_in[2];
  const float* k2 = (const float*)d_in[3];
  const float* b2 = (const float*)d_in[4];
  const float* k3 = (const float*)d_in[5];
  const float* b3 = (const float*)d_in[6];
  float* out = (float*)d_out;
  char* ws = (char*)d_ws;

  // Workspace layout (137,363,456 bytes total), all bf16:
  short* k1t = (short*)(ws);                 // 64*1024*224*2 = 29,360,128
  short* k3t = (short*)(ws + 29360128);      // 64*256*1024*2 = 33,554,432
  short* hA = (short*)(ws + 62914560);       // 64*BC*224*2   =  7,340,032
  short* h1c = (short*)(ws + 70254592);      // 64*BC*1024*2  = 33,554,432
  short* h2pc = (short*)(ws + 103809024);    // 64*BC*1024*2  = 33,554,432

  transpose_k1<<<dim3(64, 16), 256, 0, stream>>>(k1, k1t);
  transpose_k3<<<dim3(64, 8, 4), 256, 0, stream>>>(k3, k3t);
  for (int c = 0; c < 1024 / BC; ++c) {
    int bOffset = c * BC;
    gather_x<<<(64 * BC * 224) / 256, 256, 0, stream>>>(x, hA, bOffset);
    gemm_stage1<<<dim3(16, BC / 64, 64), 256, 0, stream>>>(hA, k1t, b1, h1c);
    stage2<<<dim3(64, BC / 8), 256, 0, stream>>>(h1c, k2, b2, h2pc);
    gemm_stage3<<<dim3(4, BC / 64, 64), 256, 0, stream>>>(h2pc, k3t, b3, out, bOffset);
  }
}

// Round 6
// 582.104 us; speedup vs baseline: 1.2885x; 1.1340x over previous
//
#include <hip/hip_runtime.h>

typedef __attribute__((ext_vector_type(8))) short short8;
typedef __attribute__((ext_vector_type(4))) short bfx4;
typedef __attribute__((ext_vector_type(4))) float floatx4;

__device__ __forceinline__ float bf2f(short u) {
  unsigned int i = ((unsigned int)(unsigned short)u) << 16;
  return __builtin_bit_cast(float, i);
}
__device__ __forceinline__ short f2bf(float f) {
  unsigned int x = __builtin_bit_cast(unsigned int, f);
  x += 0x7fffu + ((x >> 16) & 1u);
  return (short)(x >> 16);
}

// async global->LDS, 16B per lane. LDS dest = wave-uniform base + lane*16.
__device__ __forceinline__ void gl_lds16(const short* g, short* lds) {
  __builtin_amdgcn_global_load_lds(
      (const __attribute__((address_space(1))) unsigned int*)g,
      (__attribute__((address_space(3))) unsigned int*)lds, 16, 0, 0);
}

#define BC 256  // batch chunk

// ---- gather: x[B,6400,2] f32 -> hA[64][BC][224] bf16 (K padded 200->224) -----
__global__ __launch_bounds__(256) void gather_x(const float* __restrict__ x,
                                                short* __restrict__ hA, int bOffset) {
  int tid = blockIdx.x * 256 + threadIdx.x;
  const int total = 64 * BC * 224;
  if (tid >= total) return;
  int kp = tid % 224;
  int rem = tid / 224;
  int b_loc = rem & (BC - 1);
  int j1 = rem / BC;
  short v = 0;
  if (kp < 200) {
    int c = kp & 1;
    int w = kp >> 1;
    int wx = w / 10;
    int wy = w - wx * 10;
    int bx = j1 >> 3, by = j1 & 7;
    v = f2bf(x[(size_t)(bOffset + b_loc) * 12800 +
               ((size_t)(bx * 800 + wx * 80 + by * 10 + wy)) * 2 + c]);
  }
  hA[tid] = v;
}

// ---- k1[64][200][1024] f32 -> k1t[64][1024][224] bf16 (B^T, zero-padded) -----
// LDS-tiled, k-split x4 for parallelism/latency.
__global__ __launch_bounds__(256) void transpose_k1(const float* __restrict__ k1,
                                                    short* __restrict__ k1t) {
  const int j1 = blockIdx.x;          // 64
  const int nBase = blockIdx.y * 64;  // 16
  const int kBase = blockIdx.z * 56;  // 4
  __shared__ short tr[64][68];        // stride 136 B: 8B-aligned, 4-way-max banks
  const int t = threadIdx.x;
  const int nl = t & 63;
  const int ksub = t >> 6;
  const float* src = k1 + (size_t)j1 * 204800 + (size_t)kBase * 1024 + nBase + nl;
#pragma unroll
  for (int pass = 0; pass < 14; ++pass) {
    int kloc = pass * 4 + ksub;
    int k = kBase + kloc;
    tr[nl][kloc] = (k < 200) ? f2bf(src[kloc * 1024]) : (short)0;
  }
  __syncthreads();
  short* dstbase = k1t + ((size_t)j1 * 1024 + nBase) * 224 + kBase;
#pragma unroll
  for (int p = 0; p < 4; ++p) {
    int u = p * 256 + t;
    int row = u >> 4;
    int kq = u & 15;
    if (kq < 14) {
      bfx4 v = *(const bfx4*)&tr[row][kq * 4];
      *(bfx4*)&dstbase[row * 224 + kq * 4] = v;
    }
  }
}

// ---- k3[64][1024][200] f32 -> k3t[64][256][1024] bf16 (B^T, N padded) --------
__global__ __launch_bounds__(256) void transpose_k3(const float* __restrict__ k3,
                                                    short* __restrict__ k3t) {
  const int j3 = blockIdx.x;           // 64
  const int kBase = blockIdx.y * 128;  // 8
  const int nBase = blockIdx.z * 64;   // 4
  __shared__ short tr[64][132];
  const int t = threadIdx.x;
  const int nl = t & 63;
  const int ksub = t >> 6;
  const int nGlob = nBase + nl;
  const bool valid = (nGlob < 200);
  const float* src = k3 + (size_t)j3 * 204800 + (size_t)kBase * 200 + nGlob;
#pragma unroll 4
  for (int pass = 0; pass < 32; ++pass) {
    int k = pass * 4 + ksub;
    tr[nl][k] = valid ? f2bf(src[k * 200]) : (short)0;
  }
  __syncthreads();
  short* dstbase = k3t + ((size_t)j3 * 256 + nBase) * 1024 + kBase;
#pragma unroll
  for (int pass = 0; pass < 8; ++pass) {
    int idx = (pass * 256 + t) * 4;
    int row = idx >> 7;
    int koff = idx & 127;
    bfx4 v = *(const bfx4*)&tr[row][koff];
    *(bfx4*)&dstbase[row * 1024 + koff] = v;
  }
}

// ---- stage 1: per j1, C[BC,1024] = A[BC,224] @ Bt[1024,224]^T + b1 -----------
// m97-style: 128x128 tile, global_load_lds(16B), 4 waves x (64x64), BK=32.
__global__ __launch_bounds__(256) void gemm_stage1(const short* __restrict__ hA,
                                                   const short* __restrict__ k1t,
                                                   const float* __restrict__ b1,
                                                   short* __restrict__ h1) {
  const int j1 = blockIdx.z;
  const int mBase = blockIdx.y * 128;
  const int nBase = blockIdx.x * 128;
  __shared__ short As[128 * 32];
  __shared__ short Bs[128 * 32];
  const int tid = threadIdx.x;
  const int lane = tid & 63;
  const int wave = tid >> 6;
  const int quad = lane >> 4;
  const int l16 = lane & 15;
  const int wm = wave >> 1, wn = wave & 1;
  const int ldRow = tid >> 2;
  const int ldCol = (tid & 3) * 8;
  const short* Aj = hA + (size_t)j1 * BC * 224 + (size_t)(mBase + ldRow) * 224 + ldCol;
  const short* Bj = k1t + (size_t)j1 * 1024 * 224 + (size_t)(nBase + ldRow) * 224 + ldCol;
  short* ldsA = &As[tid * 8];
  short* ldsB = &Bs[tid * 8];
  floatx4 acc[4][4] = {};

  for (int kk = 0; kk < 224; kk += 32) {
    __syncthreads();
    gl_lds16(Aj + kk, ldsA);
    gl_lds16(Aj + 64 * 224 + kk, ldsA + 64 * 32);
    gl_lds16(Bj + kk, ldsB);
    gl_lds16(Bj + 64 * 224 + kk, ldsB + 64 * 32);
    __syncthreads();
    short8 af[4], bf[4];
#pragma unroll
    for (int mt = 0; mt < 4; ++mt)
      af[mt] = *(const short8*)&As[(wm * 64 + mt * 16 + l16) * 32 + quad * 8];
#pragma unroll
    for (int nt = 0; nt < 4; ++nt)
      bf[nt] = *(const short8*)&Bs[(wn * 64 + nt * 16 + l16) * 32 + quad * 8];
#pragma unroll
    for (int mt = 0; mt < 4; ++mt)
#pragma unroll
      for (int nt = 0; nt < 4; ++nt)
        acc[mt][nt] =
            __builtin_amdgcn_mfma_f32_16x16x32_bf16(af[mt], bf[nt], acc[mt][nt], 0, 0, 0);
  }
#pragma unroll
  for (int nt = 0; nt < 4; ++nt) {
    int n = nBase + wn * 64 + nt * 16 + l16;
    float bias = b1[j1 * 1024 + n];
#pragma unroll
    for (int mt = 0; mt < 4; ++mt) {
#pragma unroll
      for (int r = 0; r < 4; ++r) {
        int m = mBase + wm * 64 + mt * 16 + quad * 4 + r;
        h1[((size_t)j1 * BC + m) * 1024 + n] = f2bf(acc[mt][nt][r] + bias);
      }
    }
  }
}

// ---- stage 2: permute + tiny GEMMs, h1[64][BC][1024] -> h2p[64][mTot][1024] --
__global__ __launch_bounds__(256) void stage2(const short* __restrict__ h1,
                                              const float* __restrict__ k2,
                                              const float* __restrict__ b2,
                                              short* __restrict__ h2p, int mTot,
                                              int bOff2) {
  const int j1 = blockIdx.x;
  const int bBase = blockIdx.y * 8;
  __shared__ short in_s[8][1024];
  __shared__ short w_s[256 * 66];
  __shared__ float bias_s[16 * 64];
  const int tid = threadIdx.x;
#pragma unroll
  for (int ii = 0; ii < 4; ++ii) {
    int flat = (ii * 256 + tid) * 8;
    int b_loc = flat >> 10;
    int k = flat & 1023;
    *(short8*)&in_s[b_loc][k] =
        *(const short8*)&h1[((size_t)j1 * BC + bBase + b_loc) * 1024 + k];
  }
#pragma unroll
  for (int ii = 0; ii < 16; ++ii) {
    int flat = (ii * 256 + tid) * 4;
    int blk = flat >> 8;
    int within = flat & 255;
    int r = blk >> 2, b2hi = blk & 3;
    int j2 = r * 256 + j1 * 4 + b2hi;
    floatx4 v = *(const floatx4*)&k2[(size_t)j2 * 256 + within];
#pragma unroll
    for (int i = 0; i < 4; ++i) w_s[(within + i) * 66 + blk] = f2bf(v[i]);
  }
  {
    int blk = tid >> 2;
    int r2o = (tid & 3) * 4;
    int r = blk >> 2, b2hi = blk & 3;
    int j2 = r * 256 + j1 * 4 + b2hi;
#pragma unroll
    for (int i = 0; i < 4; ++i) bias_s[(r2o + i) * 64 + blk] = b2[j2 * 16 + r2o + i];
  }
  __syncthreads();
#pragma unroll
  for (int i4 = 0; i4 < 2; ++i4) {
    int idx = i4 * 256 + tid;
    int b_loc = idx >> 6;
    int rem = idx & 63;
    int r = rem >> 2;
    int b2hi = rem & 3;
    float acc[16];
#pragma unroll
    for (int r2 = 0; r2 < 16; ++r2) acc[r2] = bias_s[r2 * 64 + rem];
#pragma unroll
    for (int k = 0; k < 16; ++k) {
      float iv = bf2f(in_s[b_loc][(b2hi * 16 + k) * 16 + r]);
#pragma unroll
      for (int r2 = 0; r2 < 16; ++r2)
        acc[r2] += iv * bf2f(w_s[(k * 16 + r2) * 66 + rem]);
    }
    int j3 = r * 4 + (j1 >> 4);
    int k3o = (j1 & 15) * 64 + b2hi * 16;
    short8 o0, o1;
#pragma unroll
    for (int t = 0; t < 8; ++t) {
      o0[t] = f2bf(acc[t]);
      o1[t] = f2bf(acc[8 + t]);
    }
    short* dst = h2p + ((size_t)j3 * mTot + bOff2 + bBase + b_loc) * 1024 + k3o;
    *(short8*)&dst[0] = o0;
    *(short8*)&dst[8] = o1;
  }
}

// ---- stage 3: per j3, [M,1024] @ k3t^T (+b3), scatter to out f32 -------------
__global__ __launch_bounds__(256) void gemm_stage3(const short* __restrict__ h2p,
                                                   const short* __restrict__ k3t,
                                                   const float* __restrict__ b3,
                                                   float* __restrict__ out, int mTot,
                                                   int bOffset) {
  const int j3 = blockIdx.z;
  const int mBase = blockIdx.y * 128;
  const int nBase = blockIdx.x * 128;
  __shared__ short As[128 * 32];
  __shared__ short Bs[128 * 32];
  const int tid = threadIdx.x;
  const int lane = tid & 63;
  const int wave = tid >> 6;
  const int quad = lane >> 4;
  const int l16 = lane & 15;
  const int wm = wave >> 1, wn = wave & 1;
  const int ldRow = tid >> 2;
  const int ldCol = (tid & 3) * 8;
  const short* Aj =
      h2p + (size_t)j3 * mTot * 1024 + (size_t)(mBase + ldRow) * 1024 + ldCol;
  const short* Bj =
      k3t + (size_t)j3 * 256 * 1024 + (size_t)(nBase + ldRow) * 1024 + ldCol;
  short* ldsA = &As[tid * 8];
  short* ldsB = &Bs[tid * 8];
  floatx4 acc[4][4] = {};

  for (int kk = 0; kk < 1024; kk += 32) {
    __syncthreads();
    gl_lds16(Aj + kk, ldsA);
    gl_lds16(Aj + 64 * 1024 + kk, ldsA + 64 * 32);
    gl_lds16(Bj + kk, ldsB);
    gl_lds16(Bj + 64 * 1024 + kk, ldsB + 64 * 32);
    __syncthreads();
    short8 af[4], bf[4];
#pragma unroll
    for (int mt = 0; mt < 4; ++mt)
      af[mt] = *(const short8*)&As[(wm * 64 + mt * 16 + l16) * 32 + quad * 8];
#pragma unroll
    for (int nt = 0; nt < 4; ++nt)
      bf[nt] = *(const short8*)&Bs[(wn * 64 + nt * 16 + l16) * 32 + quad * 8];
#pragma unroll
    for (int mt = 0; mt < 4; ++mt)
#pragma unroll
      for (int nt = 0; nt < 4; ++nt)
        acc[mt][nt] =
            __builtin_amdgcn_mfma_f32_16x16x32_bf16(af[mt], bf[nt], acc[mt][nt], 0, 0, 0);
  }
  const int B2x = j3 >> 3, B2y = j3 & 7;
#pragma unroll
  for (int nt = 0; nt < 4; ++nt) {
    int n = nBase + wn * 64 + nt * 16 + l16;
    if (n < 200) {
      float bias = b3[j3 * 200 + n];
      int c = n & 1;
      int t = n >> 1;
      int w2x = t / 10, w2y = t - w2x * 10;
      int orow = B2x * 10 + w2x, ocol = B2y * 10 + w2y;
#pragma unroll
      for (int mt = 0; mt < 4; ++mt) {
#pragma unroll
        for (int r = 0; r < 4; ++r) {
          int m = bOffset + mBase + wm * 64 + mt * 16 + quad * 4 + r;
          out[(((size_t)m * 80 + orow) * 80 + ocol) * 2 + c] = acc[mt][nt][r] + bias;
        }
      }
    }
  }
}

extern "C" void kernel_launch(void* const* d_in, const int* in_sizes, int n_in,
                              void* d_out, int out_size, void* d_ws, size_t ws_size,
                              hipStream_t stream) {
  const float* x = (const float*)d_in[0];
  const float* k1 = (const float*)d_in[1];
  const float* b1 = (const float*)d_in[2];
  const float* k2 = (const float*)d_in[3];
  const float* b2 = (const float*)d_in[4];
  const float* k3 = (const float*)d_in[5];
  const float* b3 = (const float*)d_in[6];
  float* out = (float*)d_out;
  char* ws = (char*)d_ws;

  short* k1t = (short*)(ws);                // 29,360,128
  short* k3t = (short*)(ws + 29360128);     // 33,554,432
  short* hA = (short*)(ws + 62914560);      //  7,340,032
  short* h1c = (short*)(ws + 70254592);     // 33,554,432
  short* h2p = (short*)(ws + 103809024);    // 33,554,432 (chunked) / 134,217,728 (full)

  const bool full = (ws_size >= 238026752ull);  // full h2p fits
  const int mTot = full ? 1024 : BC;

  transpose_k1<<<dim3(64, 16, 4), 256, 0, stream>>>(k1, k1t);
  transpose_k3<<<dim3(64, 8, 4), 256, 0, stream>>>(k3, k3t);
  for (int c = 0; c < 1024 / BC; ++c) {
    int bOffset = c * BC;
    gather_x<<<(64 * BC * 224) / 256, 256, 0, stream>>>(x, hA, bOffset);
    gemm_stage1<<<dim3(8, BC / 128, 64), 256, 0, stream>>>(hA, k1t, b1, h1c);
    stage2<<<dim3(64, BC / 8), 256, 0, stream>>>(h1c, k2, b2, h2p, mTot,
                                                 full ? bOffset : 0);
    if (!full)
      gemm_stage3<<<dim3(2, BC / 128, 64), 256, 0, stream>>>(h2p, k3t, b3, out, BC,
                                                             bOffset);
  }
  if (full)
    gemm_stage3<<<dim3(2, 1024 / 128, 64), 256, 0, stream>>>(h2p, k3t, b3, out, 1024,
                                                             0);
}